// Round 1
// baseline (373.392 us; speedup 1.0000x reference)
//
#include <hip/hip_runtime.h>

#define L 256
#define BATCH 512
#define CIN 32
#define RNNIN 64
#define HIDN 128
#define OUTN 512

// ws layout (floats):
//   Wc     @ 0        (128*32 = 4096)   Wc[j*32+c] = sum_m W_ih[j][m]*W_in[m][c]
//   bpre   @ 4096     (128)             b_ih + b_hh + W_ih@b_in
//   hs     @ 8192     (256*512*128)     hs[t*65536 + b*128 + j]
//   pooled @ 8192+16777216 (512*128)

__global__ __launch_bounds__(128) void prep_kernel(
    const float* __restrict__ W_in, const float* __restrict__ b_in,
    const float* __restrict__ W_ih, const float* __restrict__ b_ih,
    const float* __restrict__ b_hh,
    float* __restrict__ Wc, float* __restrict__ bpre)
{
    const int j = threadIdx.x;  // 128 threads, one per hidden unit
    float acc[CIN];
#pragma unroll
    for (int c = 0; c < CIN; ++c) acc[c] = 0.f;
    float bs = b_ih[j] + b_hh[j];
    for (int m = 0; m < RNNIN; ++m) {
        float w = W_ih[j * RNNIN + m];
        bs += w * b_in[m];
#pragma unroll
        for (int c = 0; c < CIN; ++c) acc[c] += w * W_in[m * CIN + c];
    }
#pragma unroll
    for (int c = 0; c < CIN; ++c) Wc[j * CIN + c] = acc[c];
    bpre[j] = bs;
}

// One block = 2 batch rows. thread (r = tid>>7, j = tid&127) computes h[r][j].
// W_hh row j held in registers; h and x_t double-buffered in LDS (1 barrier/step).
__global__ __launch_bounds__(256) void rnn_kernel(
    const float* __restrict__ x, const float* __restrict__ h0,
    const float* __restrict__ Whh,
    const float* __restrict__ Wc, const float* __restrict__ bpre,
    float* __restrict__ hs)
{
    const int tid = threadIdx.x;
    const int j = tid & 127;
    const int r = tid >> 7;
    const int b = blockIdx.x * 2 + r;

    float whh[HIDN];
#pragma unroll
    for (int k = 0; k < HIDN; k += 4) {
        float4 v = *(const float4*)(Whh + j * HIDN + k);
        whh[k] = v.x; whh[k + 1] = v.y; whh[k + 2] = v.z; whh[k + 3] = v.w;
    }
    float wc[CIN];
#pragma unroll
    for (int c = 0; c < CIN; c += 4) {
        float4 v = *(const float4*)(Wc + j * CIN + c);
        wc[c] = v.x; wc[c + 1] = v.y; wc[c + 2] = v.z; wc[c + 3] = v.w;
    }
    const float bp = bpre[j];

    __shared__ float hbuf[2][2][HIDN];  // [phase][row][k]
    __shared__ float xbuf[2][2][CIN];   // [phase][row][c]

    hbuf[0][r][j] = h0[b * HIDN + j];
    const int lrr = tid >> 5;   // loader role (tid<64): row
    const int lcc = tid & 31;   // loader role: channel
    const float* xptr = x + (size_t)(blockIdx.x * 2 + lrr) * (CIN * L) + lcc * L;
    if (tid < 64) xbuf[0][lrr][lcc] = xptr[0];
    __syncthreads();

    float* hsp = hs + b * HIDN + j;
    for (int t = 0; t < L; ++t) {
        const int p = t & 1;
        float xn = 0.f;
        if (tid < 64 && t < L - 1) xn = xptr[t + 1];  // prefetch next x_t

        float acc = bp;
#pragma unroll
        for (int c = 0; c < CIN; c += 4) {
            float4 xv = *(const float4*)(&xbuf[p][r][c]);  // broadcast
            acc += xv.x * wc[c] + xv.y * wc[c + 1] + xv.z * wc[c + 2] + xv.w * wc[c + 3];
        }
#pragma unroll
        for (int k = 0; k < HIDN; k += 4) {
            float4 hv = *(const float4*)(&hbuf[p][r][k]);  // broadcast
            acc += hv.x * whh[k] + hv.y * whh[k + 1] + hv.z * whh[k + 2] + hv.w * whh[k + 3];
        }
        // tanh(x) = 1 - 2/(exp(2x)+1)  (stable at both extremes)
        float e = __expf(2.f * acc);
        float hn = 1.f - 2.f / (e + 1.f);

        hsp[(size_t)t * (BATCH * HIDN)] = hn;
        hbuf[p ^ 1][r][j] = hn;
        if (tid < 64 && t < L - 1) xbuf[p ^ 1][lrr][lcc] = xn;
        __syncthreads();  // step t writes (phase p^1) visible before step t+1 reads
    }
}

// Upsample 16x16 -> 32x32 (align_corners) + hardswish + mean, fused.
// Block handles (b, 32 hidden units); map staged in LDS.
__global__ __launch_bounds__(256) void pool_kernel(
    const float* __restrict__ hs, float* __restrict__ pooled)
{
    const int b = blockIdx.x >> 2;
    const int j0 = (blockIdx.x & 3) * 32;
    __shared__ float m[L][32];  // [t=y*16+x][j_off]; <=2-way conflicts (free)
    const float* src = hs + b * HIDN + j0;
    for (int idx = threadIdx.x; idx < L * 32; idx += 256) {
        int jo = idx & 31, t = idx >> 5;
        m[t][jo] = src[(size_t)t * (BATCH * HIDN) + jo];
    }
    __syncthreads();
    const int jo = threadIdx.x & 31;
    const int sub = threadIdx.x >> 5;  // 8 threads per j
    float acc = 0.f;
#pragma unroll 4
    for (int p = sub; p < 1024; p += 8) {
        int oy = p >> 5, ox = p & 31;
        float ysf = oy * (15.f / 31.f);
        int y0 = (int)ysf; float wy = ysf - (float)y0; int y1 = min(y0 + 1, 15);
        float xsf = ox * (15.f / 31.f);
        int x0 = (int)xsf; float wx = xsf - (float)x0; int x1 = min(x0 + 1, 15);
        float v00 = m[y0 * 16 + x0][jo], v01 = m[y0 * 16 + x1][jo];
        float v10 = m[y1 * 16 + x0][jo], v11 = m[y1 * 16 + x1][jo];
        float v0 = v00 + wx * (v01 - v00);
        float v1 = v10 + wx * (v11 - v10);
        float v = v0 + wy * (v1 - v0);
        float t6 = fminf(fmaxf(v + 3.f, 0.f), 6.f);
        acc += v * t6;
    }
    __shared__ float ps[8][32];
    ps[sub][jo] = acc;
    __syncthreads();
    if (threadIdx.x < 32) {
        float s = 0.f;
#pragma unroll
        for (int u = 0; u < 8; ++u) s += ps[u][threadIdx.x];
        pooled[b * HIDN + j0 + threadIdx.x] = s * (1.f / 6144.f);  // /6 hardswish, /1024 mean
    }
}

__global__ __launch_bounds__(256) void out_kernel(
    const float* __restrict__ pooled, const float* __restrict__ W_out,
    const float* __restrict__ b_out, float* __restrict__ out)
{
    const int b = blockIdx.x;
    __shared__ float pv[HIDN];
    if (threadIdx.x < HIDN) pv[threadIdx.x] = pooled[b * HIDN + threadIdx.x];
    __syncthreads();
    for (int o = threadIdx.x; o < OUTN; o += 256) {
        float acc = b_out[o];
#pragma unroll 8
        for (int k = 0; k < HIDN; k += 4) {
            float4 w = *(const float4*)(W_out + o * HIDN + k);
            acc += w.x * pv[k] + w.y * pv[k + 1] + w.z * pv[k + 2] + w.w * pv[k + 3];
        }
        out[b * OUTN + o] = acc;
    }
}

extern "C" void kernel_launch(void* const* d_in, const int* in_sizes, int n_in,
                              void* d_out, int out_size, void* d_ws, size_t ws_size,
                              hipStream_t stream)
{
    const float* x     = (const float*)d_in[0];
    const float* h0    = (const float*)d_in[1];
    const float* W_in  = (const float*)d_in[2];
    const float* b_in  = (const float*)d_in[3];
    const float* W_ih  = (const float*)d_in[4];
    const float* b_ih  = (const float*)d_in[5];
    const float* W_hh  = (const float*)d_in[6];
    const float* b_hh  = (const float*)d_in[7];
    const float* W_out = (const float*)d_in[8];
    const float* b_out = (const float*)d_in[9];
    float* out = (float*)d_out;

    float* ws     = (float*)d_ws;
    float* Wc     = ws;                      // 4096 floats
    float* bpre   = ws + 4096;               // 128 floats
    float* hs     = ws + 8192;               // 16,777,216 floats (64 MB)
    float* pooled = ws + 8192 + 16777216;    // 65,536 floats

    prep_kernel<<<1, 128, 0, stream>>>(W_in, b_in, W_ih, b_ih, b_hh, Wc, bpre);
    rnn_kernel<<<256, 256, 0, stream>>>(x, h0, W_hh, Wc, bpre, hs);
    pool_kernel<<<2048, 256, 0, stream>>>(hs, pooled);
    out_kernel<<<512, 256, 0, stream>>>(pooled, W_out, b_out, out);
}